// Round 4
// baseline (218.388 us; speedup 1.0000x reference)
//
#include <hip/hip_runtime.h>

#define TILE 16
#define RR 8
#define ND 17          // 2r+1 displacements per axis
#define PW 544         // padded dst width/height (512 + 2*16)
#define PPAD 16
#define HH 512
#define WW 512
#define CC 3
#define BB 4
#define NTILES (BB * 1024)

// float4 load with only 4-byte alignment guarantee.
typedef float f4a __attribute__((ext_vector_type(4), aligned(4)));

// ---------------- kernel 1: zero-padded dst copy + key init ----------------
__global__ __launch_bounds__(256) void pad_kernel(const float* __restrict__ dst,
                                                  float* __restrict__ P,
                                                  unsigned long long* __restrict__ keys) {
    const int gpr = PW / 4;          // 136 float4 groups per row
    const int gpi = PW * gpr;        // per image-channel
    int idx = blockIdx.x * 256 + threadIdx.x;
    if (idx < NTILES) keys[idx] = ~0ULL;
    if (idx >= BB * CC * gpi) return;
    int bc  = idx / gpi;
    int rem = idx - bc * gpi;
    int y   = rem / gpr;
    int x   = (rem - y * gpr) * 4;
    float4 v = make_float4(0.f, 0.f, 0.f, 0.f);
    if (y >= PPAD && y < PPAD + HH && x >= PPAD && x < PPAD + WW)
        v = *(const float4*)(dst + ((size_t)bc * HH + (y - PPAD)) * WW + (x - PPAD));
    *(float4*)(P + ((size_t)bc * PW + y) * PW + x) = v;
}

// x + dpp_perm(x) — VALU pipe. CTRL compile-time.
template <int CTRL>
__device__ __forceinline__ float dpp_add(float x) {
    return x + __int_as_float(
        __builtin_amdgcn_update_dpp(0, __float_as_int(x), CTRL, 0xF, 0xF, true));
}
// x + lane(x ^ 16) via ds_swizzle (LDS pipe)
__device__ __forceinline__ float swz16_add(float x) {
    int y = __builtin_amdgcn_ds_swizzle(__float_as_int(x), (16 << 10) | 0x1F);
    return x + __int_as_float(y);
}

// ---------------- kernel 2: one straight-line wave per (tile, dy) ----------
// Lane l: h = l>>5 (dx group: 0..8 / 8..16), jg = (l>>4)&1 (j half),
// i = l&15 (row). Each lane: 9 dx-accumulators over its 8-j segment.
// Reduction over lane bits 0..4 = 4 DPP stages + 1 swizzle. Lane 0 of each
// 32-half argmins its 9 sums and atomicMin's a packed (costbits<<32 | d) key.
__global__ __launch_bounds__(64, 4) void sad_kernel(const float* __restrict__ src,
                                                    const float* __restrict__ P,
                                                    const int* __restrict__ offset,
                                                    unsigned long long* __restrict__ keys) {
    // XCD banding: blocks r*8704..(r+1)*8704 assumed round-robin by %8 -> XCD r
    const int L  = blockIdx.x;          // 0 .. 4096*17-1
    const int r  = L & 7;
    const int g  = L >> 3;              // 0 .. 8703
    const int tq = g / ND;              // 0 .. 511
    const int dy = g - tq * ND;
    const int tile = r * 512 + tq;
    const int b  = tile >> 10;
    const int th = (tile >> 5) & 31;
    const int tw = tile & 31;
    const int ti = th * TILE, tj = tw * TILE;
    const int oy = offset[(b * 2 + 0) * 1024 + th * 32 + tw];
    const int ox = offset[(b * 2 + 1) * 1024 + th * 32 + tw];

    const int lane = threadIdx.x;
    const int h  = lane >> 5;
    const int jg = (lane >> 4) & 1;
    const int i  = lane & 15;

    const int rowP = ti + oy + (PPAD - RR) + dy + i;        // in [8, 543]
    const int colW = tj + ox + (PPAD - RR) + 8 * h + 8 * jg;

    // ---- all loads hoisted: 12 window f4a + 6 src f4a ----
    float W[CC][16];
    float S[CC][8];
    #pragma unroll
    for (int c = 0; c < CC; ++c) {
        const float* wp = P + ((size_t)((b * CC + c) * PW + rowP)) * PW + colW;
        f4a a0 = *(const f4a*)(wp + 0);
        f4a a1 = *(const f4a*)(wp + 4);
        f4a a2 = *(const f4a*)(wp + 8);
        f4a a3 = *(const f4a*)(wp + 12);
        W[c][0]=a0.x;  W[c][1]=a0.y;  W[c][2]=a0.z;  W[c][3]=a0.w;
        W[c][4]=a1.x;  W[c][5]=a1.y;  W[c][6]=a1.z;  W[c][7]=a1.w;
        W[c][8]=a2.x;  W[c][9]=a2.y;  W[c][10]=a2.z; W[c][11]=a2.w;
        W[c][12]=a3.x; W[c][13]=a3.y; W[c][14]=a3.z; W[c][15]=a3.w;
        const float* sp = src + ((size_t)((b * CC + c) * HH + ti + i)) * WW + tj + 8 * jg;
        f4a s0 = *(const f4a*)sp;
        f4a s1 = *(const f4a*)(sp + 4);
        S[c][0]=s0.x; S[c][1]=s0.y; S[c][2]=s0.z; S[c][3]=s0.w;
        S[c][4]=s1.x; S[c][5]=s1.y; S[c][6]=s1.z; S[c][7]=s1.w;
    }

    float acc[9];
    #pragma unroll
    for (int a = 0; a < 9; ++a) acc[a] = 0.f;
    #pragma unroll
    for (int c = 0; c < CC; ++c) {
        #pragma unroll
        for (int a = 0; a < 9; ++a) {
            float s0 = acc[a];
            #pragma unroll
            for (int jl = 0; jl < 8; ++jl)
                s0 += fabsf(W[c][a + jl] - S[c][jl]);
            acc[a] = s0;
        }
    }

    // ---- reduce over lane bits 0..4 (i and jg) within each 32-half ----
    #pragma unroll
    for (int a = 0; a < 9; ++a) {
        float x = acc[a];
        x = dpp_add<0xB1>(x);     // quad_perm xor1
        x = dpp_add<0x4E>(x);     // quad_perm xor2
        x = dpp_add<0x141>(x);    // row_half_mirror == xor4 (bits 0,1 done)
        x = dpp_add<0x140>(x);    // row_mirror      == xor8 (bits 0..2 done)
        x = swz16_add(x);         // xor16 (jg)
        acc[a] = x;
    }

    if ((lane & 31) == 0) {
        // argmin over this half's dx values; a ascending + strict < keeps
        // the smallest d. h1 skips a=0 (dx=8 is h0's, avoids order-dup).
        float bc = acc[0];
        int   ba = 0;
        #pragma unroll
        for (int a = 1; a < 9; ++a)
            if (acc[a] < bc) { bc = acc[a]; ba = a; }
        if (h == 1 && ba == 0) {          // recompute skipping a=0
            bc = acc[1]; ba = 1;
            #pragma unroll
            for (int a = 2; a < 9; ++a)
                if (acc[a] < bc) { bc = acc[a]; ba = a; }
        }
        const unsigned d = (unsigned)(dy * ND + 8 * h + ba);
        unsigned long long key =
            ((unsigned long long)__float_as_uint(bc) << 32) | d;
        atomicMin(keys + tile, key);
    }
}

// ---------------- kernel 3: read winner key, write new_off + gather --------
__global__ __launch_bounds__(64) void gather_kernel(const float* __restrict__ P,
                                                    const int* __restrict__ offset,
                                                    const unsigned long long* __restrict__ keys,
                                                    float* __restrict__ out) {
    const int tile = blockIdx.x;
    const int b  = tile >> 10;
    const int th = (tile >> 5) & 31;
    const int tw = tile & 31;
    const int ti = th * TILE, tj = tw * TILE;
    const int t  = threadIdx.x;
    const int oy = offset[(b * 2 + 0) * 1024 + th * 32 + tw];
    const int ox = offset[(b * 2 + 1) * 1024 + th * 32 + tw];
    const int d  = (int)(keys[tile] & 0xFFFFFFFFu);
    const int bdy = d / ND;
    const int bdx = d - bdy * ND;

    if (t == 0) out[(b * 2 + 0) * 1024 + th * 32 + tw] = (float)(oy + bdy - RR);
    if (t == 1) out[(b * 2 + 1) * 1024 + th * 32 + tw] = (float)(ox + bdx - RR);

    float* aligned = out + BB * 2 * 1024;
    const int pr = ti + oy + bdy + (PPAD - RR);
    const int pc = tj + ox + bdx + (PPAD - RR);
    #pragma unroll
    for (int k = 0; k < 12; ++k) {
        int idx = t + 64 * k;              // 0..767 -> (c, ii, jj)
        int c  = idx >> 8;
        int ii = (idx >> 4) & 15;
        int jj = idx & 15;
        aligned[((size_t)((b * CC + c) * HH + ti + ii)) * WW + tj + jj] =
            P[((size_t)((b * CC + c) * PW + pr + ii)) * PW + pc + jj];
    }
}

extern "C" void kernel_launch(void* const* d_in, const int* in_sizes, int n_in,
                              void* d_out, int out_size, void* d_ws, size_t ws_size,
                              hipStream_t stream) {
    const float* src    = (const float*)d_in[0];
    const float* dst    = (const float*)d_in[1];
    const int*   offset = (const int*)d_in[2];
    float*       out    = (float*)d_out;

    float* P = (float*)d_ws;                          // 12*544*544 floats = 14.2 MB
    unsigned long long* keys =
        (unsigned long long*)(P + (size_t)BB * CC * PW * PW);  // 32 KB, 8B-aligned

    const int pad_groups = BB * CC * PW * (PW / 4);   // 887808 = 3468 * 256
    pad_kernel<<<dim3(pad_groups / 256), 256, 0, stream>>>(dst, P, keys);
    sad_kernel<<<dim3(NTILES * ND), 64, 0, stream>>>(src, P, offset, keys);
    gather_kernel<<<dim3(NTILES), 64, 0, stream>>>(P, offset, keys, out);
}

// Round 5
// 135.105 us; speedup vs baseline: 1.6164x; 1.6164x over previous
//
#include <hip/hip_runtime.h>

#define TILE 16
#define RR 8
#define ND 17          // 2r+1 displacements per axis
#define PW 544         // padded dst width/height (512 + 2*16)
#define PPAD 16
#define HH 512
#define WW 512
#define CC 3
#define BB 4
#define NTILES (BB * 1024)

typedef float f4a __attribute__((ext_vector_type(4), aligned(4)));
typedef unsigned long long u64;

// ---------------- kernel 1: zero-padded dst copy + key init ----------------
__global__ __launch_bounds__(256) void pad_kernel(const float* __restrict__ dst,
                                                  float* __restrict__ P,
                                                  u64* __restrict__ keys) {
    const int gpr = PW / 4;          // 136 float4 groups per row
    const int gpi = PW * gpr;        // per image-channel
    int idx = blockIdx.x * 256 + threadIdx.x;
    if (idx < NTILES) keys[idx] = ~0ULL;
    if (idx >= BB * CC * gpi) return;
    int bc  = idx / gpi;
    int rem = idx - bc * gpi;
    int y   = rem / gpr;
    int x   = (rem - y * gpr) * 4;
    float4 v = make_float4(0.f, 0.f, 0.f, 0.f);
    if (y >= PPAD && y < PPAD + HH && x >= PPAD && x < PPAD + WW)
        v = *(const float4*)(dst + ((size_t)bc * HH + (y - PPAD)) * WW + (x - PPAD));
    *(float4*)(P + ((size_t)bc * PW + y) * PW + x) = v;
}

// x + dpp_perm(x) — VALU pipe.
template <int CTRL>
__device__ __forceinline__ float dpp_add(float x) {
    return x + __int_as_float(
        __builtin_amdgcn_update_dpp(0, __float_as_int(x), CTRL, 0xF, 0xF, true));
}
// x + lane(x ^ MASK) via ds_swizzle (LDS pipe, MASK < 32)
template <int MASK>
__device__ __forceinline__ float swz_add(float x) {
    int y = __builtin_amdgcn_ds_swizzle(__float_as_int(x), (MASK << 10) | 0x1F);
    return x + __int_as_float(y);
}

// ---------------- kernel 2: SAD, 9 waves per block = 9 dy of one tile ------
// Two blocks per tile: even block dy=0..8, odd block dy=8..16 (dy=8 twice —
// idempotent under atomicMin). Lane l: h=bit0 (dx group 0..8 / 8..16),
// jg=bit1 (8-wide j half), i=bits2..5 (row). Each lane: 9 dx-accs over its
// 8-j segment. Reduction spans lane bits 1..5; h halves combine via shfl xor1.
__global__ __launch_bounds__(576, 4) void sad_kernel(const float* __restrict__ src,
                                                     const float* __restrict__ P,
                                                     const int* __restrict__ offset,
                                                     u64* __restrict__ keys) {
    const int B = blockIdx.x;            // 0..8191
    const int r = B & 7;                 // XCD band (round-robin %8 assumption)
    const int q = B >> 3;                // 0..1023
    const int tile = r * 512 + (q >> 1);
    const int dy = 8 * (q & 1) + (int)(threadIdx.x >> 6);   // 0..8 or 8..16

    const int b  = tile >> 10;
    const int th = (tile >> 5) & 31;
    const int tw = tile & 31;
    const int ti = th * TILE, tj = tw * TILE;
    const int oy = offset[(b * 2 + 0) * 1024 + th * 32 + tw];
    const int ox = offset[(b * 2 + 1) * 1024 + th * 32 + tw];

    const int l  = threadIdx.x & 63;
    const int h  = l & 1;
    const int jg = (l >> 1) & 1;
    const int i  = l >> 2;

    const int rowP = ti + oy + (PPAD - RR) + dy + i;          // in [8, 543]
    const int colW = tj + ox + (PPAD - RR) + 8 * (h + jg);    // 4B-aligned

    // ---- hoisted loads: 12 window f4a + 6 src f4a ----
    float W[CC][16];
    float S[CC][8];
    #pragma unroll
    for (int c = 0; c < CC; ++c) {
        const float* wp = P + ((size_t)((b * CC + c) * PW + rowP)) * PW + colW;
        f4a a0 = *(const f4a*)(wp + 0);
        f4a a1 = *(const f4a*)(wp + 4);
        f4a a2 = *(const f4a*)(wp + 8);
        f4a a3 = *(const f4a*)(wp + 12);
        W[c][0]=a0.x;  W[c][1]=a0.y;  W[c][2]=a0.z;  W[c][3]=a0.w;
        W[c][4]=a1.x;  W[c][5]=a1.y;  W[c][6]=a1.z;  W[c][7]=a1.w;
        W[c][8]=a2.x;  W[c][9]=a2.y;  W[c][10]=a2.z; W[c][11]=a2.w;
        W[c][12]=a3.x; W[c][13]=a3.y; W[c][14]=a3.z; W[c][15]=a3.w;
        const float* sp = src + ((size_t)((b * CC + c) * HH + ti + i)) * WW + tj + 8 * jg;
        f4a s0 = *(const f4a*)sp;
        f4a s1 = *(const f4a*)(sp + 4);
        S[c][0]=s0.x; S[c][1]=s0.y; S[c][2]=s0.z; S[c][3]=s0.w;
        S[c][4]=s1.x; S[c][5]=s1.y; S[c][6]=s1.z; S[c][7]=s1.w;
    }

    float acc[9];
    #pragma unroll
    for (int a = 0; a < 9; ++a) acc[a] = 0.f;
    #pragma unroll
    for (int c = 0; c < CC; ++c) {
        #pragma unroll
        for (int a = 0; a < 9; ++a) {
            float s0 = acc[a];
            #pragma unroll
            for (int jl = 0; jl < 8; ++jl)
                s0 += fabsf(W[c][a + jl] - S[c][jl]);
            acc[a] = s0;
        }
    }

    // ---- reduce over lane bits 1..5 (jg and i); bit0 (h) preserved ----
    #pragma unroll
    for (int a = 0; a < 9; ++a) {
        float x = acc[a];
        x = dpp_add<0x4E>(x);     // quad_perm [2,3,0,1] = xor2 (jg)
        x = swz_add<4>(x);        // xor4  (i bit 0)
        x = swz_add<8>(x);        // xor8  (i bit 1)
        x = swz_add<16>(x);       // xor16 (i bit 2)
        x += __shfl_xor(x, 32);   // xor32 (i bit 3)
        acc[a] = x;
    }

    // ---- per-lane argmin over this h-group's dx; h=1 skips a=0 (dx=8 dup).
    // ascending a + strict < keeps the smallest dx on ties.
    float bc = h ? acc[1] : acc[0];
    int   ba = h;
    #pragma unroll
    for (int a = 1; a < 9; ++a)
        if (a > h && acc[a] < bc) { bc = acc[a]; ba = a; }
    const unsigned d = (unsigned)(dy * ND + 8 * h + ba);
    u64 key = ((u64)__float_as_uint(bc) << 32) | d;   // cost>=0: bit order = numeric
    u64 ok  = __shfl_xor(key, 1);                     // other h half
    if (ok < key) key = ok;                           // equal cost -> smaller d wins
    if (l == 0) atomicMin(keys + tile, key);
}

// ---------------- kernel 3: read winner key, write new_off + gather --------
__global__ __launch_bounds__(256) void gather_kernel(const float* __restrict__ P,
                                                     const int* __restrict__ offset,
                                                     const u64* __restrict__ keys,
                                                     float* __restrict__ out) {
    const int tile = blockIdx.x * 4 + (int)(threadIdx.x >> 6);
    const int b  = tile >> 10;
    const int th = (tile >> 5) & 31;
    const int tw = tile & 31;
    const int ti = th * TILE, tj = tw * TILE;
    const int t  = threadIdx.x & 63;
    const int oy = offset[(b * 2 + 0) * 1024 + th * 32 + tw];
    const int ox = offset[(b * 2 + 1) * 1024 + th * 32 + tw];
    const int d  = (int)(keys[tile] & 0xFFFFFFFFu);
    const int bdy = d / ND;
    const int bdx = d - bdy * ND;

    if (t == 0) out[(b * 2 + 0) * 1024 + th * 32 + tw] = (float)(oy + bdy - RR);
    if (t == 1) out[(b * 2 + 1) * 1024 + th * 32 + tw] = (float)(ox + bdx - RR);

    float* aligned = out + BB * 2 * 1024;
    const int pr = ti + oy + bdy + (PPAD - RR);
    const int pc = tj + ox + bdx + (PPAD - RR);
    #pragma unroll
    for (int k = 0; k < 12; ++k) {
        int idx = t + 64 * k;              // 0..767 -> (c, ii, jj)
        int c  = idx >> 8;
        int ii = (idx >> 4) & 15;
        int jj = idx & 15;
        aligned[((size_t)((b * CC + c) * HH + ti + ii)) * WW + tj + jj] =
            P[((size_t)((b * CC + c) * PW + pr + ii)) * PW + pc + jj];
    }
}

extern "C" void kernel_launch(void* const* d_in, const int* in_sizes, int n_in,
                              void* d_out, int out_size, void* d_ws, size_t ws_size,
                              hipStream_t stream) {
    const float* src    = (const float*)d_in[0];
    const float* dst    = (const float*)d_in[1];
    const int*   offset = (const int*)d_in[2];
    float*       out    = (float*)d_out;

    float* P = (float*)d_ws;                          // 12*544*544 floats = 14.2 MB
    u64* keys = (u64*)(P + (size_t)BB * CC * PW * PW);  // 32 KB, 8B-aligned

    const int pad_groups = BB * CC * PW * (PW / 4);   // 887808 = 3468 * 256
    pad_kernel<<<dim3(pad_groups / 256), 256, 0, stream>>>(dst, P, keys);
    sad_kernel<<<dim3(NTILES * 2), 576, 0, stream>>>(src, P, offset, keys);
    gather_kernel<<<dim3(NTILES / 4), 256, 0, stream>>>(P, offset, keys, out);
}

// Round 6
// 130.326 us; speedup vs baseline: 1.6757x; 1.0367x over previous
//
#include <hip/hip_runtime.h>

#define TILE 16
#define RR 8
#define ND 17          // 2r+1 displacements per axis
#define HH 512
#define WW 512
#define CC 3
#define BB 4
#define WROWS 32       // window rows/cols in LDS
#define WSTR 36        // window LDS row stride (conflict-free for b128 phases)
#define SSTR 20        // src LDS row stride
#define BLK 576        // 9 waves per block = one tile

typedef float f4a __attribute__((ext_vector_type(4), aligned(4)));
typedef unsigned long long u64;

// x + dpp_perm(x) — VALU pipe.
template <int CTRL>
__device__ __forceinline__ float dpp_add(float x) {
    return x + __int_as_float(
        __builtin_amdgcn_update_dpp(0, __float_as_int(x), CTRL, 0xF, 0xF, true));
}
// x + lane(x ^ MASK) via ds_swizzle (LDS pipe, MASK < 32)
template <int MASK>
__device__ __forceinline__ float swz_add(float x) {
    int y = __builtin_amdgcn_ds_swizzle(__float_as_int(x), (MASK << 10) | 0x1F);
    return x + __int_as_float(y);
}

// one dy-pass: SAD over the LDS window, reduce, per-lane-pair argmin -> key
__device__ __forceinline__ u64 sad_pass(const float* Wl, const float S[CC][8],
                                        int dy, int i, int h, int jg) {
    float acc[9];
    #pragma unroll
    for (int a = 0; a < 9; ++a) acc[a] = 0.f;
    #pragma unroll
    for (int c = 0; c < CC; ++c) {
        const int wb = c * (WROWS * WSTR) + (dy + i) * WSTR + 8 * (h + jg);
        f4a a0 = *(const f4a*)&Wl[wb + 0];
        f4a a1 = *(const f4a*)&Wl[wb + 4];
        f4a a2 = *(const f4a*)&Wl[wb + 8];
        f4a a3 = *(const f4a*)&Wl[wb + 12];
        float W16[16] = { a0.x, a0.y, a0.z, a0.w, a1.x, a1.y, a1.z, a1.w,
                          a2.x, a2.y, a2.z, a2.w, a3.x, a3.y, a3.z, a3.w };
        #pragma unroll
        for (int a = 0; a < 9; ++a) {
            float s0 = acc[a];
            #pragma unroll
            for (int jl = 0; jl < 8; ++jl)
                s0 += fabsf(W16[a + jl] - S[c][jl]);
            acc[a] = s0;
        }
    }
    // reduce over lane bits 1..5 (jg, i); bit0 (h) preserved
    #pragma unroll
    for (int a = 0; a < 9; ++a) {
        float x = acc[a];
        x = dpp_add<0x4E>(x);     // xor2 (jg)
        x = swz_add<4>(x);        // xor4
        x = swz_add<8>(x);        // xor8
        x = swz_add<16>(x);       // xor16
        x += __shfl_xor(x, 32);   // xor32
        acc[a] = x;
    }
    // per-lane argmin over this h-group's dx (h=1 skips a=0: dx=8 dup);
    // ascending a + strict < keeps the smallest dx on ties.
    float bc = h ? acc[1] : acc[0];
    int   ba = h;
    #pragma unroll
    for (int a = 1; a < 9; ++a)
        if (a > h && acc[a] < bc) { bc = acc[a]; ba = a; }
    const unsigned d = (unsigned)(dy * ND + 8 * h + ba);
    u64 key = ((u64)__float_as_uint(bc) << 32) | d;   // cost>=0: bit order = numeric
    u64 ok  = __shfl_xor(key, 1);                     // other h half
    return ok < key ? ok : key;
}

__global__ __launch_bounds__(BLK, 6) void tile_kernel(const float* __restrict__ src,
                                                      const float* __restrict__ dst,
                                                      const int* __restrict__ offset,
                                                      float* __restrict__ out) {
    __shared__ float Wl[CC * WROWS * WSTR];   // 13824 B
    __shared__ float Sl[CC * TILE * SSTR];    //  3840 B
    __shared__ u64   keyL[9];

    const int bid  = blockIdx.x;
    const int tile = ((bid & 7) << 9) | (bid >> 3);  // XCD-banding swizzle
    const int b  = tile >> 10;
    const int th = (tile >> 5) & 31;
    const int tw = tile & 31;
    const int ti = th * TILE, tj = tw * TILE;
    const int oy = offset[(b * 2 + 0) * 1024 + th * 32 + tw];
    const int ox = offset[(b * 2 + 1) * 1024 + th * 32 + tw];
    const int t  = threadIdx.x;

    // ---- stage 3x32x32 dst window (zero-padded) coalesced into LDS ----
    const int gy0 = ti + oy - RR;
    const int gx0 = tj + ox - RR;
    for (int k = t; k < CC * WROWS * 8; k += BLK) {   // 768 float4 chunks
        int c   = k >> 8;
        int rem = k & 255;
        int row = rem >> 3;
        int cc  = (rem & 7) << 2;
        int gy = gy0 + row;
        int gx = gx0 + cc;
        float4 v = make_float4(0.f, 0.f, 0.f, 0.f);
        if ((unsigned)gy < HH) {
            const float* p = dst + ((size_t)(b * CC + c) * HH + gy) * WW;
            if ((unsigned)gx <= WW - 4) {
                f4a u = *(const f4a*)(p + gx);
                v = make_float4(u.x, u.y, u.z, u.w);
            } else {
                float* ve = (float*)&v;
                #pragma unroll
                for (int e = 0; e < 4; ++e) {
                    int g = gx + e;
                    if ((unsigned)g < WW) ve[e] = p[g];
                }
            }
        }
        *(f4a*)&Wl[c * (WROWS * WSTR) + row * WSTR + cc] = *(f4a*)&v;
    }
    // ---- stage 3x16x16 src tile (always in-bounds, aligned) ----
    if (t >= 192 && t < 384) {
        int k   = t - 192;                 // 192 float4 chunks
        int c   = k >> 6;
        int rem = k & 63;
        int row = rem >> 2;
        int cc  = (rem & 3) << 2;
        f4a v = *(const f4a*)(src + ((size_t)(b * CC + c) * HH + ti + row) * WW + tj + cc);
        *(f4a*)&Sl[c * (TILE * SSTR) + row * SSTR + cc] = v;
    }
    __syncthreads();

    // lane map: h=bit0 (dx 0..8 / 8..16), jg=bit1 (j half), i=bits2..5 (row)
    const int wv = t >> 6;
    const int l  = t & 63;
    const int h  = l & 1;
    const int jg = (l >> 1) & 1;
    const int i  = l >> 2;

    float S[CC][8];
    #pragma unroll
    for (int c = 0; c < CC; ++c) {
        const int sb = c * (TILE * SSTR) + i * SSTR + 8 * jg;
        f4a s0 = *(const f4a*)&Sl[sb];
        f4a s1 = *(const f4a*)&Sl[sb + 4];
        S[c][0]=s0.x; S[c][1]=s0.y; S[c][2]=s0.z; S[c][3]=s0.w;
        S[c][4]=s1.x; S[c][5]=s1.y; S[c][6]=s1.z; S[c][7]=s1.w;
    }

    u64 bestkey = sad_pass(Wl, S, wv, i, h, jg);          // dy = 0..8
    const int dy2 = 9 + wv;                               // dy = 9..16 (wave 8 skips)
    if (dy2 < ND) {
        u64 k2 = sad_pass(Wl, S, dy2, i, h, jg);
        if (k2 < bestkey) bestkey = k2;
    }
    if (l == 0) keyL[wv] = bestkey;
    __syncthreads();

    // block-wide winner (u64 min; d in low bits gives exact smallest-d ties)
    u64 wk = keyL[0];
    #pragma unroll
    for (int w = 1; w < 9; ++w) { u64 kw = keyL[w]; if (kw < wk) wk = kw; }
    const int d   = (int)(wk & 0xFFFFFFFFu);
    const int bdy = d / ND;
    const int bdx = d - bdy * ND;

    if (t == 0) out[(b * 2 + 0) * 1024 + th * 32 + tw] = (float)(oy + bdy - RR);
    if (t == 1) out[(b * 2 + 1) * 1024 + th * 32 + tw] = (float)(ox + bdx - RR);

    // aligned tile is already in the LDS window
    float* aligned = out + BB * 2 * 1024;
    for (int e = t; e < CC * TILE * TILE; e += BLK) {
        int c  = e >> 8;
        int ii = (e >> 4) & 15;
        int jj = e & 15;
        aligned[((size_t)(b * CC + c) * HH + ti + ii) * WW + tj + jj] =
            Wl[c * (WROWS * WSTR) + (bdy + ii) * WSTR + bdx + jj];
    }
}

extern "C" void kernel_launch(void* const* d_in, const int* in_sizes, int n_in,
                              void* d_out, int out_size, void* d_ws, size_t ws_size,
                              hipStream_t stream) {
    const float* src    = (const float*)d_in[0];
    const float* dst    = (const float*)d_in[1];
    const int*   offset = (const int*)d_in[2];
    float*       out    = (float*)d_out;
    tile_kernel<<<dim3(BB * 1024), BLK, 0, stream>>>(src, dst, offset, out);
}